// Round 5
// baseline (502.254 us; speedup 1.0000x reference)
//
#include <hip/hip_runtime.h>

#define NE 800000
#define D  64
#define K1 192
#define AST 200  // A-tile row stride in bf16 (192 + 8 pad)

typedef __bf16 bf16x4v __attribute__((ext_vector_type(4)));
typedef __bf16 bf16x8  __attribute__((ext_vector_type(8)));
typedef float  f32x4   __attribute__((ext_vector_type(4)));

// Convert W1 (192x64, k-major) -> W1^T bf16 (64x192, n-major) at ws[0],
// and W2 (64x64) -> W2^T bf16 (64x64) at ws[12288]. 16384 threads total.
__global__ void prep_weights(const float* __restrict__ W1,
                             const float* __restrict__ W2,
                             __bf16* __restrict__ ws) {
  int i = blockIdx.x * 256 + threadIdx.x;
  if (i < K1 * D) {
    int k = i >> 6, n = i & 63;
    ws[n * K1 + k] = (__bf16)W1[i];
  } else {
    int j = i - K1 * D;
    int k = j >> 6, n = j & 63;
    ws[K1 * D + n * D + k] = (__bf16)W2[j];
  }
}

// Per-wave LDS ordering only (LDS pipe is in-order per wave); the asm memory
// clobber also stops the compiler from reordering LDS accesses across it.
__device__ __forceinline__ void wave_lds_fence() {
  __asm__ volatile("s_waitcnt lgkmcnt(0)" ::: "memory");
}

__device__ __forceinline__ float silu(float x) {
  return x * __builtin_amdgcn_rcpf(1.f + __expf(-x));
}

// R5: w1t moved OUT of LDS. The 24.6 KB W1^T table is read straight from the
// global workspace (L2/L3-resident, every CU hits it every ~1us -> ~100% L2
// hit). LDS/block drops 52224 -> 26624 B => 6 blocks/CU instead of 3.
// The compiler's own occupancy target (~84 VGPR ~ 6 waves/EU) now matches the
// LDS limit, so no spill pressure (R2/R3/R4 lesson: don't fight the
// allocator with long-lived register prefetches).
template <bool USE_WS>
__global__ __launch_bounds__(256, 4)
void edge_kernel(const float* __restrict__ nodes, const float* __restrict__ ef,
                 const int* __restrict__ srci, const int* __restrict__ dsti,
                 const float* __restrict__ W1, const float* __restrict__ b1,
                 const float* __restrict__ W2, const float* __restrict__ b2,
                 const float* __restrict__ gmm, const float* __restrict__ bta,
                 const __bf16* __restrict__ wsw, float* __restrict__ out) {
  // LDS: 4*6400 (A-tiles) + 1024 (bias) = 26624 B -> 6 blocks/CU.
  __shared__ __align__(16) __bf16 atile_all[4][16 * AST];
  __shared__ float sb1[64], sb2[64], sg[64], sbt[64];

  const int tid = threadIdx.x;
  const int wave = tid >> 6, lane = tid & 63;
  const int quad = lane >> 4, m16 = lane & 15;  // quad doubles as r4, m16 as c4

  if (tid < 64)       sb1[tid]       = b1[tid];
  else if (tid < 128) sb2[tid - 64]  = b2[tid - 64];
  else if (tid < 192) sg[tid - 128]  = gmm[tid - 128];
  else                sbt[tid - 192] = bta[tid - 192];

  // W1^T B-fragment row pointers: loop-invariant, 4 per lane. Fragment for
  // (ki, nt) lives at w1p[nt] + ki*32 elements (64 B imm offset -> folds).
  const __bf16* w1p[4];
  if (USE_WS) {
    #pragma unroll
    for (int nt = 0; nt < 4; ++nt)
      w1p[nt] = wsw + (size_t)(nt * 16 + m16) * K1 + quad * 8;
  }

  // W2^T B-fragments in registers (loop-invariant): 8 x bf16x8 = 32 VGPR.
  bf16x8 w2f[2][4];
  if (USE_WS) {
    const __bf16* w2t = wsw + K1 * D;  // 64x64, n-major
    #pragma unroll
    for (int ki = 0; ki < 2; ++ki)
      #pragma unroll
      for (int nt = 0; nt < 4; ++nt)
        w2f[ki][nt] = *(const bf16x8*)&w2t[(nt * 16 + m16) * 64 + ki * 32 + quad * 8];
  } else {
    #pragma unroll
    for (int ki = 0; ki < 2; ++ki)
      #pragma unroll
      for (int nt = 0; nt < 4; ++nt) {
        const int n = nt * 16 + m16;
        #pragma unroll
        for (int j = 0; j < 8; ++j)
          w2f[ki][nt][j] = (__bf16)W2[(ki * 32 + quad * 8 + j) * 64 + n];
      }
  }
  __syncthreads();  // bias staging visible to all waves

  __bf16* At = atile_all[wave];
  float*  Af = (float*)At;  // fp32 view for output staging (row stride 100 f32)

  #pragma unroll 1
  for (int t = 0; t < 4; ++t) {
    const int base = blockIdx.x * 256 + wave * 64 + t * 16;

    // ---- coalesced staging: 16 edges' concat rows -> A-tile (bf16) ----
    // lane = 16 lanes per row: row = i*4 + quad-group, 16B chunk = m16.
    int si[4], di[4];
    #pragma unroll
    for (int i = 0; i < 4; ++i) {
      si[i] = srci[base + i * 4 + quad];
      di[i] = dsti[base + i * 4 + quad];
    }
    #pragma unroll
    for (int i = 0; i < 4; ++i) {
      const int row = i * 4 + quad;
      f32x4 sv = *(const f32x4*)(nodes + (size_t)si[i] * D + m16 * 4);
      f32x4 dv = *(const f32x4*)(nodes + (size_t)di[i] * D + m16 * 4);
      f32x4 ev = *(const f32x4*)(ef + (size_t)(base + row) * D + m16 * 4);
      bf16x4v sb, db, eb;
      #pragma unroll
      for (int j = 0; j < 4; ++j) {
        sb[j] = (__bf16)sv[j]; db[j] = (__bf16)dv[j]; eb[j] = (__bf16)ev[j];
      }
      *(bf16x4v*)&At[row * AST +       m16 * 4] = sb;
      *(bf16x4v*)&At[row * AST +  64 + m16 * 4] = db;
      *(bf16x4v*)&At[row * AST + 128 + m16 * 4] = eb;
    }
    wave_lds_fence();

    // ---- layer 1: [16 x 192] @ [192 x 64], B streamed from L2 ----
    f32x4 acc[4] = {};
    #pragma unroll
    for (int ki = 0; ki < 6; ++ki) {
      bf16x8 a = *(const bf16x8*)&At[m16 * AST + ki * 32 + quad * 8];
      #pragma unroll
      for (int nt = 0; nt < 4; ++nt) {
        bf16x8 bfv;
        if (USE_WS) {
          bfv = *(const bf16x8*)(w1p[nt] + ki * 32);
        } else {
          const int n = nt * 16 + m16;
          #pragma unroll
          for (int j = 0; j < 8; ++j)
            bfv[j] = (__bf16)W1[(ki * 32 + quad * 8 + j) * 64 + n];
        }
        acc[nt] = __builtin_amdgcn_mfma_f32_16x16x32_bf16(a, bfv, acc[nt], 0, 0, 0);
      }
    }

    // bias + SiLU; h1 -> A-tile cols 0..63 (src/dst slabs dead, ef preserved)
    #pragma unroll
    for (int nt = 0; nt < 4; ++nt) {
      const int c = nt * 16 + m16;
      const float bb = sb1[c];
      #pragma unroll
      for (int r = 0; r < 4; ++r)
        At[(quad * 4 + r) * AST + c] = (__bf16)silu(acc[nt][r] + bb);
    }
    wave_lds_fence();

    // ---- layer 2: [16 x 64] @ [64 x 64] ----
    f32x4 acc2[4] = {};
    #pragma unroll
    for (int ki = 0; ki < 2; ++ki) {
      bf16x8 a = *(const bf16x8*)&At[m16 * AST + ki * 32 + quad * 8];
      #pragma unroll
      for (int nt = 0; nt < 4; ++nt)
        acc2[nt] = __builtin_amdgcn_mfma_f32_16x16x32_bf16(a, w2f[ki][nt], acc2[nt], 0, 0, 0);
    }

    // ---- epilogue: bias + SiLU + residual(bf16 ef from LDS) + LayerNorm ----
    #pragma unroll
    for (int r = 0; r < 4; ++r) {
      const int row = quad * 4 + r;
      float x[4];
      float sum = 0.f;
      #pragma unroll
      for (int nt = 0; nt < 4; ++nt) {
        const int c = nt * 16 + m16;
        float h = silu(acc2[nt][r] + sb2[c]);
        float efv = (float)At[row * AST + 128 + c];
        x[nt] = efv + h;
        sum += x[nt];
      }
      float sq = x[0] * x[0] + x[1] * x[1] + x[2] * x[2] + x[3] * x[3];
      #pragma unroll
      for (int off = 1; off < 16; off <<= 1) {
        sum += __shfl_xor(sum, off);
        sq  += __shfl_xor(sq, off);
      }
      const float mean = sum * (1.f / 64.f);
      const float var  = sq * (1.f / 64.f) - mean * mean;
      const float rstd = rsqrtf(var + 1e-5f);
      // stage fp32 out rows in A-tile float view (cols 0..63; disjoint from
      // the bf16 ef slab at float cols 64..95)
      #pragma unroll
      for (int nt = 0; nt < 4; ++nt) {
        const int c = nt * 16 + m16;
        Af[row * (AST / 2) + c] = (x[nt] - mean) * rstd * sg[c] + sbt[c];
      }
    }
    wave_lds_fence();

    // ---- coalesced store: 4 dense 1-KB stores per wave ----
    #pragma unroll
    for (int i = 0; i < 4; ++i) {
      const int row = i * 4 + quad;
      f32x4 ov = *(const f32x4*)&Af[row * (AST / 2) + m16 * 4];
      *(f32x4*)(out + (size_t)(base + row) * D + m16 * 4) = ov;
    }
    wave_lds_fence();  // WAR: next t's staging rewrites the A-tile
  }
}

extern "C" void kernel_launch(void* const* d_in, const int* in_sizes, int n_in,
                              void* d_out, int out_size, void* d_ws, size_t ws_size,
                              hipStream_t stream) {
  const float* nodes = (const float*)d_in[0];
  const float* ef    = (const float*)d_in[1];
  const int*   srci  = (const int*)d_in[2];
  const int*   dsti  = (const int*)d_in[3];
  const float* W1    = (const float*)d_in[4];
  const float* b1    = (const float*)d_in[5];
  const float* W2    = (const float*)d_in[6];
  const float* b2    = (const float*)d_in[7];
  const float* gmm   = (const float*)d_in[8];
  const float* bta   = (const float*)d_in[9];
  float* out = (float*)d_out;

  const int blocks = NE / 256;  // 3125, exact
  if (ws_size >= (size_t)(K1 * D + D * D) * 2) {
    prep_weights<<<64, 256, 0, stream>>>(W1, W2, (__bf16*)d_ws);
    edge_kernel<true><<<blocks, 256, 0, stream>>>(
        nodes, ef, srci, dsti, W1, b1, W2, b2, gmm, bta,
        (const __bf16*)d_ws, out);
  } else {
    edge_kernel<false><<<blocks, 256, 0, stream>>>(
        nodes, ef, srci, dsti, W1, b1, W2, b2, gmm, bta, nullptr, out);
  }
}

// Round 6
// 398.110 us; speedup vs baseline: 1.2616x; 1.2616x over previous
//
#include <hip/hip_runtime.h>

#define NE 800000
#define NN 50000
#define D  64
#define K1 192
#define AST 200  // A-tile / w1t row stride in bf16 (192 + 8 pad)
#define WSW_ELEMS (K1 * D + D * D)  // 16384 bf16 weight elems

typedef __bf16 bf16x4v __attribute__((ext_vector_type(4)));
typedef __bf16 bf16x8  __attribute__((ext_vector_type(8)));
typedef float  f32x4   __attribute__((ext_vector_type(4)));

// blocks 0..63: W1 (192x64) -> W1^T bf16 at ws[0], W2 -> W2^T at ws[12288].
// blocks 64.. (if do_nodes): nodes fp32 [50000x64] -> bf16 at ws[16384].
// bf16 node table = 6.4 MB (vs 12.8 fp32): larger L2-resident fraction for
// the random per-edge gathers + half the bytes per gather. Numerically
// identical to the old path (nodes were already rounded to bf16 at staging).
__global__ void prep_all(const float* __restrict__ W1,
                         const float* __restrict__ W2,
                         const float* __restrict__ nodes,
                         __bf16* __restrict__ ws, int do_nodes) {
  const int b = blockIdx.x;
  if (b < 64) {
    int i = b * 256 + threadIdx.x;
    if (i < K1 * D) {
      int k = i >> 6, n = i & 63;
      ws[n * K1 + k] = (__bf16)W1[i];
    } else {
      int j = i - K1 * D;
      int k = j >> 6, n = j & 63;
      ws[K1 * D + n * D + k] = (__bf16)W2[j];
    }
  } else if (do_nodes) {
    __bf16* nb = ws + WSW_ELEMS;
    const int nvec = NN * D / 4;  // 800000 float4 groups
    for (int v = (b - 64) * 256 + threadIdx.x; v < nvec; v += 2048 * 256) {
      f32x4 x = *(const f32x4*)(nodes + (size_t)v * 4);
      bf16x4v y;
      #pragma unroll
      for (int j = 0; j < 4; ++j) y[j] = (__bf16)x[j];
      *(bf16x4v*)(nb + (size_t)v * 4) = y;
    }
  }
}

// Per-wave LDS ordering only (LDS pipe is in-order per wave); the asm memory
// clobber also stops the compiler from reordering LDS accesses across it.
__device__ __forceinline__ void wave_lds_fence() {
  __asm__ volatile("s_waitcnt lgkmcnt(0)" ::: "memory");
}

__device__ __forceinline__ float silu(float x) {
  return x * __builtin_amdgcn_rcpf(1.f + __expf(-x));
}

// MODE 2: ws weights + bf16 node table; MODE 1: ws weights, fp32 nodes;
// MODE 0: no workspace (all from fp32 globals).
template <int MODE>
__global__ __launch_bounds__(256, 3)
void edge_kernel(const float* __restrict__ nodes, const float* __restrict__ ef,
                 const int* __restrict__ srci, const int* __restrict__ dsti,
                 const float* __restrict__ W1, const float* __restrict__ b1,
                 const float* __restrict__ W2, const float* __restrict__ b2,
                 const float* __restrict__ gmm, const float* __restrict__ bta,
                 const __bf16* __restrict__ wsw, float* __restrict__ out) {
  // LDS: 25600 (w1t) + 4*6400 (A-tiles) + 1024 = 52224 B -> 3 blocks/CU.
  __shared__ __align__(16) __bf16 w1t[64 * AST];
  __shared__ __align__(16) __bf16 atile_all[4][16 * AST];
  __shared__ float sb1[64], sb2[64], sg[64], sbt[64];

  const int tid = threadIdx.x;
  const int wave = tid >> 6, lane = tid & 63;
  const int quad = lane >> 4, m16 = lane & 15;  // quad doubles as r4, m16 as c4

  if (MODE >= 1) {
    const uint2* s1 = (const uint2*)wsw;  // 3072 x 8B chunks of W1^T
    for (int c = tid; c < 3072; c += 256) {
      int n = c / 48, kc = c - n * 48;
      *(uint2*)&w1t[n * AST + kc * 4] = s1[c];
    }
  } else {
    for (int i = tid; i < K1 * D; i += 256) {
      int k = i >> 6, n = i & 63;
      w1t[n * AST + k] = (__bf16)W1[i];
    }
  }
  if (tid < 64)       sb1[tid]       = b1[tid];
  else if (tid < 128) sb2[tid - 64]  = b2[tid - 64];
  else if (tid < 192) sg[tid - 128]  = gmm[tid - 128];
  else                sbt[tid - 192] = bta[tid - 192];

  // W2^T B-fragments in registers (loop-invariant): 8 x bf16x8 = 32 VGPR.
  bf16x8 w2f[2][4];
  if (MODE >= 1) {
    const __bf16* w2t = wsw + K1 * D;  // 64x64, n-major
    #pragma unroll
    for (int ki = 0; ki < 2; ++ki)
      #pragma unroll
      for (int nt = 0; nt < 4; ++nt)
        w2f[ki][nt] = *(const bf16x8*)&w2t[(nt * 16 + m16) * 64 + ki * 32 + quad * 8];
  } else {
    #pragma unroll
    for (int ki = 0; ki < 2; ++ki)
      #pragma unroll
      for (int nt = 0; nt < 4; ++nt) {
        const int n = nt * 16 + m16;
        #pragma unroll
        for (int j = 0; j < 8; ++j)
          w2f[ki][nt][j] = (__bf16)W2[(ki * 32 + quad * 8 + j) * 64 + n];
      }
  }
  __syncthreads();  // w1t + bias staging visible to all waves

  __bf16* At = atile_all[wave];
  float*  Af = (float*)At;  // fp32 view for output staging (row stride 100 f32)

  const __bf16* nb = (MODE == 2) ? (wsw + WSW_ELEMS) : nullptr;

  #pragma unroll 1
  for (int t = 0; t < 4; ++t) {
    const int base = blockIdx.x * 256 + wave * 64 + t * 16;

    // ---- coalesced staging: 16 edges' concat rows -> A-tile (bf16) ----
    // lane = 16 lanes per row: row = i*4 + quad-group, 16B chunk = m16.
    int si[4], di[4];
    #pragma unroll
    for (int i = 0; i < 4; ++i) {
      si[i] = srci[base + i * 4 + quad];
      di[i] = dsti[base + i * 4 + quad];
    }
    #pragma unroll
    for (int i = 0; i < 4; ++i) {
      const int row = i * 4 + quad;
      f32x4 ev = *(const f32x4*)(ef + (size_t)(base + row) * D + m16 * 4);
      bf16x4v sb, db, eb;
      if (MODE == 2) {
        // bf16 node table: direct 8B gather, no conversion on the hot path.
        sb = *(const bf16x4v*)(nb + (size_t)si[i] * D + m16 * 4);
        db = *(const bf16x4v*)(nb + (size_t)di[i] * D + m16 * 4);
      } else {
        f32x4 sv = *(const f32x4*)(nodes + (size_t)si[i] * D + m16 * 4);
        f32x4 dv = *(const f32x4*)(nodes + (size_t)di[i] * D + m16 * 4);
        #pragma unroll
        for (int j = 0; j < 4; ++j) { sb[j] = (__bf16)sv[j]; db[j] = (__bf16)dv[j]; }
      }
      #pragma unroll
      for (int j = 0; j < 4; ++j) eb[j] = (__bf16)ev[j];
      *(bf16x4v*)&At[row * AST +       m16 * 4] = sb;
      *(bf16x4v*)&At[row * AST +  64 + m16 * 4] = db;
      *(bf16x4v*)&At[row * AST + 128 + m16 * 4] = eb;
    }
    wave_lds_fence();

    // ---- layer 1: [16 x 192] @ [192 x 64] ----
    f32x4 acc[4] = {};
    #pragma unroll
    for (int ki = 0; ki < 6; ++ki) {
      bf16x8 a = *(const bf16x8*)&At[m16 * AST + ki * 32 + quad * 8];
      #pragma unroll
      for (int nt = 0; nt < 4; ++nt) {
        bf16x8 bfv = *(const bf16x8*)&w1t[(nt * 16 + m16) * AST + ki * 32 + quad * 8];
        acc[nt] = __builtin_amdgcn_mfma_f32_16x16x32_bf16(a, bfv, acc[nt], 0, 0, 0);
      }
    }

    // bias + SiLU; h1 -> A-tile cols 0..63 (src/dst slabs dead, ef preserved)
    #pragma unroll
    for (int nt = 0; nt < 4; ++nt) {
      const int c = nt * 16 + m16;
      const float bb = sb1[c];
      #pragma unroll
      for (int r = 0; r < 4; ++r)
        At[(quad * 4 + r) * AST + c] = (__bf16)silu(acc[nt][r] + bb);
    }
    wave_lds_fence();

    // ---- layer 2: [16 x 64] @ [64 x 64] ----
    f32x4 acc2[4] = {};
    #pragma unroll
    for (int ki = 0; ki < 2; ++ki) {
      bf16x8 a = *(const bf16x8*)&At[m16 * AST + ki * 32 + quad * 8];
      #pragma unroll
      for (int nt = 0; nt < 4; ++nt)
        acc2[nt] = __builtin_amdgcn_mfma_f32_16x16x32_bf16(a, w2f[ki][nt], acc2[nt], 0, 0, 0);
    }

    // ---- epilogue: bias + SiLU + residual(bf16 ef from LDS) + LayerNorm ----
    #pragma unroll
    for (int r = 0; r < 4; ++r) {
      const int row = quad * 4 + r;
      float x[4];
      float sum = 0.f;
      #pragma unroll
      for (int nt = 0; nt < 4; ++nt) {
        const int c = nt * 16 + m16;
        float h = silu(acc2[nt][r] + sb2[c]);
        float efv = (float)At[row * AST + 128 + c];
        x[nt] = efv + h;
        sum += x[nt];
      }
      float sq = x[0] * x[0] + x[1] * x[1] + x[2] * x[2] + x[3] * x[3];
      #pragma unroll
      for (int off = 1; off < 16; off <<= 1) {
        sum += __shfl_xor(sum, off);
        sq  += __shfl_xor(sq, off);
      }
      const float mean = sum * (1.f / 64.f);
      const float var  = sq * (1.f / 64.f) - mean * mean;
      const float rstd = rsqrtf(var + 1e-5f);
      // stage fp32 out rows in A-tile float view (cols 0..63; disjoint from
      // the bf16 ef slab at float cols 64..95)
      #pragma unroll
      for (int nt = 0; nt < 4; ++nt) {
        const int c = nt * 16 + m16;
        Af[row * (AST / 2) + c] = (x[nt] - mean) * rstd * sg[c] + sbt[c];
      }
    }
    wave_lds_fence();

    // ---- coalesced store: 4 dense 1-KB stores per wave ----
    #pragma unroll
    for (int i = 0; i < 4; ++i) {
      const int row = i * 4 + quad;
      f32x4 ov = *(const f32x4*)&Af[row * (AST / 2) + m16 * 4];
      *(f32x4*)(out + (size_t)(base + row) * D + m16 * 4) = ov;
    }
    wave_lds_fence();  // WAR: next t's staging rewrites the A-tile
  }
}

extern "C" void kernel_launch(void* const* d_in, const int* in_sizes, int n_in,
                              void* d_out, int out_size, void* d_ws, size_t ws_size,
                              hipStream_t stream) {
  const float* nodes = (const float*)d_in[0];
  const float* ef    = (const float*)d_in[1];
  const int*   srci  = (const int*)d_in[2];
  const int*   dsti  = (const int*)d_in[3];
  const float* W1    = (const float*)d_in[4];
  const float* b1    = (const float*)d_in[5];
  const float* W2    = (const float*)d_in[6];
  const float* b2    = (const float*)d_in[7];
  const float* gmm   = (const float*)d_in[8];
  const float* bta   = (const float*)d_in[9];
  float* out = (float*)d_out;

  const int blocks = NE / 256;  // 3125, exact
  const size_t WS_W = (size_t)WSW_ELEMS * 2;                 // 32768 B
  const size_t WS_FULL = WS_W + (size_t)NN * D * 2;          // + 6.4 MB nodes

  if (ws_size >= WS_FULL) {
    prep_all<<<64 + 2048, 256, 0, stream>>>(W1, W2, nodes, (__bf16*)d_ws, 1);
    edge_kernel<2><<<blocks, 256, 0, stream>>>(
        nodes, ef, srci, dsti, W1, b1, W2, b2, gmm, bta,
        (const __bf16*)d_ws, out);
  } else if (ws_size >= WS_W) {
    prep_all<<<64, 256, 0, stream>>>(W1, W2, nodes, (__bf16*)d_ws, 0);
    edge_kernel<1><<<blocks, 256, 0, stream>>>(
        nodes, ef, srci, dsti, W1, b1, W2, b2, gmm, bta,
        (const __bf16*)d_ws, out);
  } else {
    edge_kernel<0><<<blocks, 256, 0, stream>>>(
        nodes, ef, srci, dsti, W1, b1, W2, b2, gmm, bta, nullptr, out);
  }
}

// Round 7
// 392.960 us; speedup vs baseline: 1.2781x; 1.0131x over previous
//
#include <hip/hip_runtime.h>

#define NE 800000
#define NN 50000
#define D  64
#define K1 192
#define AST 200  // A-tile / w1t row stride in bf16 (192 + 8 pad)
#define WSW_ELEMS (K1 * D + D * D)  // 16384 bf16 weight elems

typedef __bf16 bf16x4v __attribute__((ext_vector_type(4)));
typedef __bf16 bf16x8  __attribute__((ext_vector_type(8)));
typedef float  f32x4   __attribute__((ext_vector_type(4)));

// blocks 0..63: W1 (192x64) -> W1^T bf16 at ws[0], W2 -> W2^T at ws[12288].
// blocks 64.. (if do_nodes): nodes fp32 [50000x64] -> bf16 at ws[16384].
__global__ void prep_all(const float* __restrict__ W1,
                         const float* __restrict__ W2,
                         const float* __restrict__ nodes,
                         __bf16* __restrict__ ws, int do_nodes) {
  const int b = blockIdx.x;
  if (b < 64) {
    int i = b * 256 + threadIdx.x;
    if (i < K1 * D) {
      int k = i >> 6, n = i & 63;
      ws[n * K1 + k] = (__bf16)W1[i];
    } else {
      int j = i - K1 * D;
      int k = j >> 6, n = j & 63;
      ws[K1 * D + n * D + k] = (__bf16)W2[j];
    }
  } else if (do_nodes) {
    __bf16* nb = ws + WSW_ELEMS;
    const int nvec = NN * D / 4;  // 800000 float4 groups
    for (int v = (b - 64) * 256 + threadIdx.x; v < nvec; v += 2048 * 256) {
      f32x4 x = *(const f32x4*)(nodes + (size_t)v * 4);
      bf16x4v y;
      #pragma unroll
      for (int j = 0; j < 4; ++j) y[j] = (__bf16)x[j];
      *(bf16x4v*)(nb + (size_t)v * 4) = y;
    }
  }
}

// Per-wave LDS ordering only (LDS pipe is in-order per wave); the asm memory
// clobber also stops the compiler from reordering LDS accesses across it.
// lgkmcnt only: in-flight GLOBAL loads (vmcnt) survive -> cross-tile gather
// prefetch stays in flight across all fences.
__device__ __forceinline__ void wave_lds_fence() {
  __asm__ volatile("s_waitcnt lgkmcnt(0)" ::: "memory");
}

__device__ __forceinline__ float silu(float x) {
  return x * __builtin_amdgcn_rcpf(1.f + __expf(-x));
}

// MODE 2: ws weights + bf16 node table; MODE 1: ws weights, fp32 nodes;
// MODE 0: no workspace.
//
// amdgpu_waves_per_eu(3,3): R3/R4 post-mortem — the allocator pins its budget
// to the 6-waves/EU tier (84 VGPR) and SPILLS any extra live state, even
// though LDS caps occupancy at 3 waves/EU. Forcing max=3 raises the register
// budget to 168 VGPR at zero occupancy cost, which is what the cross-tile
// gather prefetch needs (~+45 VGPR).
template <int MODE>
__global__ __launch_bounds__(256)
__attribute__((amdgpu_waves_per_eu(3, 3)))
void edge_kernel(const float* __restrict__ nodes, const float* __restrict__ ef,
                 const int* __restrict__ srci, const int* __restrict__ dsti,
                 const float* __restrict__ W1, const float* __restrict__ b1,
                 const float* __restrict__ W2, const float* __restrict__ b2,
                 const float* __restrict__ gmm, const float* __restrict__ bta,
                 const __bf16* __restrict__ wsw, float* __restrict__ out) {
  // LDS: 25600 (w1t) + 4*6400 (A-tiles) + 1024 = 52224 B -> 3 blocks/CU.
  __shared__ __align__(16) __bf16 w1t[64 * AST];
  __shared__ __align__(16) __bf16 atile_all[4][16 * AST];
  __shared__ float sb1[64], sb2[64], sg[64], sbt[64];

  const int tid = threadIdx.x;
  const int wave = tid >> 6, lane = tid & 63;
  const int quad = lane >> 4, m16 = lane & 15;  // quad doubles as r4, m16 as c4

  if (MODE >= 1) {
    const uint2* s1 = (const uint2*)wsw;  // 3072 x 8B chunks of W1^T
    for (int c = tid; c < 3072; c += 256) {
      int n = c / 48, kc = c - n * 48;
      *(uint2*)&w1t[n * AST + kc * 4] = s1[c];
    }
  } else {
    for (int i = tid; i < K1 * D; i += 256) {
      int k = i >> 6, n = i & 63;
      w1t[n * AST + k] = (__bf16)W1[i];
    }
  }
  if (tid < 64)       sb1[tid]       = b1[tid];
  else if (tid < 128) sb2[tid - 64]  = b2[tid - 64];
  else if (tid < 192) sg[tid - 128]  = gmm[tid - 128];
  else                sbt[tid - 192] = bta[tid - 192];

  // W2^T B-fragments in registers (loop-invariant): 8 x bf16x8 = 32 VGPR.
  bf16x8 w2f[2][4];
  if (MODE >= 1) {
    const __bf16* w2t = wsw + K1 * D;  // 64x64, n-major
    #pragma unroll
    for (int ki = 0; ki < 2; ++ki)
      #pragma unroll
      for (int nt = 0; nt < 4; ++nt)
        w2f[ki][nt] = *(const bf16x8*)&w2t[(nt * 16 + m16) * 64 + ki * 32 + quad * 8];
  } else {
    #pragma unroll
    for (int ki = 0; ki < 2; ++ki)
      #pragma unroll
      for (int nt = 0; nt < 4; ++nt) {
        const int n = nt * 16 + m16;
        #pragma unroll
        for (int j = 0; j < 8; ++j)
          w2f[ki][nt][j] = (__bf16)W2[(ki * 32 + quad * 8 + j) * 64 + n];
      }
  }
  __syncthreads();  // w1t + bias staging visible to all waves

  __bf16* At = atile_all[wave];

  const __bf16* nb = (MODE == 2) ? (wsw + WSW_ELEMS) : nullptr;
  const int wbase = blockIdx.x * 256 + wave * 64;

  // ---- gather register state (single buffer: consumed at staging of tile t,
  // refilled post-layer1 for tile t+1). MODE 2: bf16 8B gathers = 16 VGPR.
  bf16x4v sb[4], db[4];
  f32x4 svf[4], dvf[4];  // MODE<2 only (DCE'd in MODE 2)
  f32x4 ev[4];
  int si[4], di[4];

  // prologue: tile 0 idx + gathers
  #pragma unroll
  for (int i = 0; i < 4; ++i) {
    si[i] = srci[wbase + i * 4 + quad];
    di[i] = dsti[wbase + i * 4 + quad];
  }
  #pragma unroll
  for (int i = 0; i < 4; ++i) {
    const int row = i * 4 + quad;
    if (MODE == 2) {
      sb[i] = *(const bf16x4v*)(nb + (size_t)si[i] * D + m16 * 4);
      db[i] = *(const bf16x4v*)(nb + (size_t)di[i] * D + m16 * 4);
    } else {
      svf[i] = *(const f32x4*)(nodes + (size_t)si[i] * D + m16 * 4);
      dvf[i] = *(const f32x4*)(nodes + (size_t)di[i] * D + m16 * 4);
    }
    ev[i] = *(const f32x4*)(ef + (size_t)(wbase + row) * D + m16 * 4);
  }

  #pragma unroll
  for (int t = 0; t < 4; ++t) {
    const int base = wbase + t * 16;

    // ---- stage current tile's gather registers -> A-tile (bf16) ----
    #pragma unroll
    for (int i = 0; i < 4; ++i) {
      const int row = i * 4 + quad;
      bf16x4v s_, d_, e_;
      if (MODE == 2) {
        s_ = sb[i]; d_ = db[i];
      } else {
        #pragma unroll
        for (int j = 0; j < 4; ++j) { s_[j] = (__bf16)svf[i][j]; d_[j] = (__bf16)dvf[i][j]; }
      }
      #pragma unroll
      for (int j = 0; j < 4; ++j) e_[j] = (__bf16)ev[i][j];
      *(bf16x4v*)&At[row * AST +       m16 * 4] = s_;
      *(bf16x4v*)&At[row * AST +  64 + m16 * 4] = d_;
      *(bf16x4v*)&At[row * AST + 128 + m16 * 4] = e_;
    }

    // ---- prefetch next tile's INDICES now (L2-hit ~200cy, covered by the
    // fence + layer-1 below; needed at the post-layer1 gather issue). ----
    if (t < 3) {
      #pragma unroll
      for (int i = 0; i < 4; ++i) {
        si[i] = srci[base + 16 + i * 4 + quad];
        di[i] = dsti[base + 16 + i * 4 + quad];
      }
    }
    wave_lds_fence();

    // ---- layer 1: [16 x 192] @ [192 x 64] ----
    f32x4 acc[4] = {};
    #pragma unroll
    for (int ki = 0; ki < 6; ++ki) {
      bf16x8 a = *(const bf16x8*)&At[m16 * AST + ki * 32 + quad * 8];
      #pragma unroll
      for (int nt = 0; nt < 4; ++nt) {
        bf16x8 bfv = *(const bf16x8*)&w1t[(nt * 16 + m16) * AST + ki * 32 + quad * 8];
        acc[nt] = __builtin_amdgcn_mfma_f32_16x16x32_bf16(a, bfv, acc[nt], 0, 0, 0);
      }
    }

    // ---- T14 issue point: next tile's gathers, placed AFTER the layer-1
    // pressure peak. Latency hides under h1-writeback + layer2 + epilogue.
    // sched_barriers pin placement (no hoist into layer1, no sink to use). ----
    if (t < 3) {
      __builtin_amdgcn_sched_barrier(0);
      #pragma unroll
      for (int i = 0; i < 4; ++i) {
        const int row = i * 4 + quad;
        if (MODE == 2) {
          sb[i] = *(const bf16x4v*)(nb + (size_t)si[i] * D + m16 * 4);
          db[i] = *(const bf16x4v*)(nb + (size_t)di[i] * D + m16 * 4);
        } else {
          svf[i] = *(const f32x4*)(nodes + (size_t)si[i] * D + m16 * 4);
          dvf[i] = *(const f32x4*)(nodes + (size_t)di[i] * D + m16 * 4);
        }
        ev[i] = *(const f32x4*)(ef + (size_t)(base + 16 + row) * D + m16 * 4);
      }
      __builtin_amdgcn_sched_barrier(0);
    }

    // bias + SiLU; h1 -> A-tile cols 0..63 (src/dst slabs dead, ef preserved)
    #pragma unroll
    for (int nt = 0; nt < 4; ++nt) {
      const int c = nt * 16 + m16;
      const float bb = sb1[c];
      #pragma unroll
      for (int r = 0; r < 4; ++r)
        At[(quad * 4 + r) * AST + c] = (__bf16)silu(acc[nt][r] + bb);
    }
    wave_lds_fence();

    // ---- layer 2: [16 x 64] @ [64 x 64] ----
    f32x4 acc2[4] = {};
    #pragma unroll
    for (int ki = 0; ki < 2; ++ki) {
      bf16x8 a = *(const bf16x8*)&At[m16 * AST + ki * 32 + quad * 8];
      #pragma unroll
      for (int nt = 0; nt < 4; ++nt)
        acc2[nt] = __builtin_amdgcn_mfma_f32_16x16x32_bf16(a, w2f[ki][nt], acc2[nt], 0, 0, 0);
    }

    // ---- epilogue: bias + SiLU + residual(bf16 ef from LDS) + LayerNorm,
    // stores go DIRECT to global (16 dword stores = 4x64B segments each);
    // the fp32 LDS out-staging round trip + its fence are gone. ----
    #pragma unroll
    for (int r = 0; r < 4; ++r) {
      const int row = quad * 4 + r;
      float x[4];
      float sum = 0.f;
      #pragma unroll
      for (int nt = 0; nt < 4; ++nt) {
        const int c = nt * 16 + m16;
        float h = silu(acc2[nt][r] + sb2[c]);
        float efv = (float)At[row * AST + 128 + c];
        x[nt] = efv + h;
        sum += x[nt];
      }
      float sq = x[0] * x[0] + x[1] * x[1] + x[2] * x[2] + x[3] * x[3];
      #pragma unroll
      for (int off = 1; off < 16; off <<= 1) {
        sum += __shfl_xor(sum, off);
        sq  += __shfl_xor(sq, off);
      }
      const float mean = sum * (1.f / 64.f);
      const float var  = sq * (1.f / 64.f) - mean * mean;
      const float rstd = rsqrtf(var + 1e-5f);
      #pragma unroll
      for (int nt = 0; nt < 4; ++nt) {
        const int c = nt * 16 + m16;
        out[(size_t)(base + row) * D + c] = (x[nt] - mean) * rstd * sg[c] + sbt[c];
      }
    }
    wave_lds_fence();  // WAR: epilogue ef-reads done before next staging
  }
}

extern "C" void kernel_launch(void* const* d_in, const int* in_sizes, int n_in,
                              void* d_out, int out_size, void* d_ws, size_t ws_size,
                              hipStream_t stream) {
  const float* nodes = (const float*)d_in[0];
  const float* ef    = (const float*)d_in[1];
  const int*   srci  = (const int*)d_in[2];
  const int*   dsti  = (const int*)d_in[3];
  const float* W1    = (const float*)d_in[4];
  const float* b1    = (const float*)d_in[5];
  const float* W2    = (const float*)d_in[6];
  const float* b2    = (const float*)d_in[7];
  const float* gmm   = (const float*)d_in[8];
  const float* bta   = (const float*)d_in[9];
  float* out = (float*)d_out;

  const int blocks = NE / 256;  // 3125, exact
  const size_t WS_W = (size_t)WSW_ELEMS * 2;                 // 32768 B
  const size_t WS_FULL = WS_W + (size_t)NN * D * 2;          // + 6.4 MB nodes

  if (ws_size >= WS_FULL) {
    prep_all<<<64 + 2048, 256, 0, stream>>>(W1, W2, nodes, (__bf16*)d_ws, 1);
    edge_kernel<2><<<blocks, 256, 0, stream>>>(
        nodes, ef, srci, dsti, W1, b1, W2, b2, gmm, bta,
        (const __bf16*)d_ws, out);
  } else if (ws_size >= WS_W) {
    prep_all<<<64, 256, 0, stream>>>(W1, W2, nodes, (__bf16*)d_ws, 0);
    edge_kernel<1><<<blocks, 256, 0, stream>>>(
        nodes, ef, srci, dsti, W1, b1, W2, b2, gmm, bta,
        (const __bf16*)d_ws, out);
  } else {
    edge_kernel<0><<<blocks, 256, 0, stream>>>(
        nodes, ef, srci, dsti, W1, b1, W2, b2, gmm, bta, nullptr, out);
  }
}